// Round 4
// baseline (148.384 us; speedup 1.0000x reference)
//
#include <hip/hip_runtime.h>
#include <hip/hip_bf16.h>

typedef __attribute__((ext_vector_type(8))) short short8v;   // 8 bf16 = 4 VGPRs
typedef __attribute__((ext_vector_type(4))) float f32x4;

#define N_ROWS 4096
#define M_ROWS 65536
#define DIM 64

#define AS1C(p) ((const __attribute__((address_space(1))) void*)(p))
#define AS3(p)  ((__attribute__((address_space(3))) void*)(p))

__device__ inline unsigned short f2bf(float f) {
  unsigned u = __float_as_uint(f);
  unsigned r = (u + 0x7FFFu + ((u >> 16) & 1u)) >> 16;   // RNE
  return (unsigned short)r;
}
__device__ inline float bf2f(unsigned short s) {
  return __uint_as_float(((unsigned)s) << 16);
}

// ---------- fused: convert sf f32->bf16 AND partial G = SF^T SF ----------
// 512 blocks x 256 thr; block handles 128 rows. Each thread converts 32 f32
// (8 float4), writes sf16 + LDS tile, then 4x4-register-blocked partial G.
__global__ __launch_bounds__(256) void cvt_g_kernel(const float* __restrict__ sf,
                                                    unsigned short* __restrict__ sf16,
                                                    float* __restrict__ Gp) {
  __shared__ unsigned short tile[128 * DIM];   // 16 KB
  const int tid = threadIdx.x;
  const size_t base = (size_t)blockIdx.x * 128 * DIM;

#pragma unroll
  for (int j = 0; j < 8; ++j) {
    const int e = tid * 4 + j * 1024;          // flat f32 index within block
    float4 v = *reinterpret_cast<const float4*>(sf + base + e);
    ushort4 o;
    o.x = f2bf(v.x); o.y = f2bf(v.y); o.z = f2bf(v.z); o.w = f2bf(v.w);
    *reinterpret_cast<ushort4*>(sf16 + base + e) = o;
    *reinterpret_cast<ushort4*>(&tile[e]) = o;
  }
  __syncthreads();

  const int d1 = (tid & 15) * 4;
  const int d2 = (tid >> 4) * 4;
  float acc[4][4];
#pragma unroll
  for (int i = 0; i < 4; ++i)
#pragma unroll
    for (int j = 0; j < 4; ++j) acc[i][j] = 0.f;

#pragma unroll 8
  for (int m = 0; m < 128; ++m) {
    ushort4 a4 = *reinterpret_cast<const ushort4*>(&tile[m * DIM + d1]);
    ushort4 b4 = *reinterpret_cast<const ushort4*>(&tile[m * DIM + d2]);
    float a[4] = {bf2f(a4.x), bf2f(a4.y), bf2f(a4.z), bf2f(a4.w)};
    float b[4] = {bf2f(b4.x), bf2f(b4.y), bf2f(b4.z), bf2f(b4.w)};
#pragma unroll
    for (int i = 0; i < 4; ++i)
#pragma unroll
      for (int j = 0; j < 4; ++j) acc[i][j] += a[i] * b[j];
  }
#pragma unroll
  for (int i = 0; i < 4; ++i)
#pragma unroll
    for (int j = 0; j < 4; ++j)
      Gp[(size_t)blockIdx.x * 4096 + (d1 + i) * DIM + (d2 + j)] = acc[i][j];
}

// ---------- Spart[n][bm] = sum over m-chunk bm of |u_n . sf_m| ----------
// grid (8, 64): block owns 512 n-rows x 1024 m-rows. 4 waves; wave owns 128
// n-rows (8x 16-row subtiles). B double-buffered in LDS via global_load_lds,
// K-step = 128 m-rows (16 KB), 8 steps, 1 barrier/step.
// LDS layout [kpart(8)][row(128)][8 bf16] via per-lane global source addr.
__global__ __launch_bounds__(256) void s_kernel(const float* __restrict__ u,
                                                const unsigned short* __restrict__ sf16,
                                                float* __restrict__ Spart) {
  __shared__ unsigned short Bt[2][8192];   // 2 x 16 KB
  const int bn = blockIdx.x;          // 0..7
  const int bm = blockIdx.y;          // 0..63
  const int tid = threadIdx.x;
  const int wid = tid >> 6;
  const int lane = tid & 63;
  const int l15 = lane & 15;
  const int lg  = lane >> 4;          // 0..3
  const int n0 = bn * 512 + wid * 128;
  const int mbase = bm * 1024;

  // A fragments: convert u rows f32->bf16 in-register. A[row=l15][k=kf*32+lg*8+j]
  short8v au[8][2];
#pragma unroll
  for (int st = 0; st < 8; ++st) {
#pragma unroll
    for (int kf = 0; kf < 2; ++kf) {
      const float* ap = u + (size_t)(n0 + st * 16 + l15) * DIM + kf * 32 + lg * 8;
      float4 f0 = *reinterpret_cast<const float4*>(ap);
      float4 f1 = *reinterpret_cast<const float4*>(ap + 4);
      short8v v;
      v[0] = (short)f2bf(f0.x); v[1] = (short)f2bf(f0.y);
      v[2] = (short)f2bf(f0.z); v[3] = (short)f2bf(f0.w);
      v[4] = (short)f2bf(f1.x); v[5] = (short)f2bf(f1.y);
      v[6] = (short)f2bf(f1.z); v[7] = (short)f2bf(f1.w);
      au[st][kf] = v;
    }
  }

  f32x4 sacc[8];
#pragma unroll
  for (int st = 0; st < 8; ++st) sacc[st] = (f32x4){0.f, 0.f, 0.f, 0.f};

  // Staging: 16 (kp, h) pairs; wave w takes idx = w*4..w*4+3, kp=idx>>1, h=idx&1.
  // LDS dest linear (wave-uniform base + lane*16B); per-lane global src:
  //   Bt[buf][kp*1024 + h*512 + lane*8] <- sf16[(mbase + step*128 + h*64 + lane)*64 + kp*8]
#define STAGE(buf, step)                                                       \
  {                                                                            \
    _Pragma("unroll") for (int j = 0; j < 4; ++j) {                            \
      const int idx = wid * 4 + j;                                             \
      const int kp = idx >> 1;                                                 \
      const int h = idx & 1;                                                   \
      const unsigned short* g =                                                \
          sf16 + (size_t)(mbase + (step) * 128 + h * 64 + lane) * DIM + kp * 8;\
      __builtin_amdgcn_global_load_lds(AS1C(g), AS3(&Bt[buf][kp * 1024 + h * 512]), 16, 0, 0); \
    }                                                                          \
  }

  STAGE(0, 0);
  for (int s = 0; s < 8; ++s) {
    __syncthreads();                    // buf s&1 ready (vmcnt drained here)
    if (s < 7) STAGE((s + 1) & 1, s + 1);
    const unsigned short* B = &Bt[s & 1][0];
#pragma unroll
    for (int g = 0; g < 8; ++g) {       // 16-row m sub-tiles
      short8v b0 = *reinterpret_cast<const short8v*>(
          &B[(size_t)lg * 1024 + (g * 16 + l15) * 8]);          // kpart = lg
      short8v b1 = *reinterpret_cast<const short8v*>(
          &B[(size_t)(4 + lg) * 1024 + (g * 16 + l15) * 8]);    // kpart = 4+lg
#pragma unroll
      for (int st = 0; st < 8; ++st) {
        f32x4 acc = (f32x4){0.f, 0.f, 0.f, 0.f};
        acc = __builtin_amdgcn_mfma_f32_16x16x32_bf16(au[st][0], b0, acc, 0, 0, 0);
        acc = __builtin_amdgcn_mfma_f32_16x16x32_bf16(au[st][1], b1, acc, 0, 0, 0);
        sacc[st][0] += fabsf(acc[0]);
        sacc[st][1] += fabsf(acc[1]);
        sacc[st][2] += fabsf(acc[2]);
        sacc[st][3] += fabsf(acc[3]);
      }
    }
  }
#undef STAGE

  // reduce across the 16 m-columns (lane bits 0..3)
#pragma unroll
  for (int off = 1; off < 16; off <<= 1) {
#pragma unroll
    for (int st = 0; st < 8; ++st) {
#pragma unroll
      for (int r = 0; r < 4; ++r)
        sacc[st][r] += __shfl_xor(sacc[st][r], off, 64);
    }
  }
  if (l15 == 0) {
#pragma unroll
    for (int st = 0; st < 8; ++st)
#pragma unroll
      for (int r = 0; r < 4; ++r)
        Spart[(size_t)(n0 + st * 16 + lg * 4 + r) * 64 + bm] = sacc[st][r];
  }
}

// ---------- reduce Gp (512 partials) -> G row j, then P[j] = G[j] @ W^T ----------
__global__ __launch_bounds__(256) void gp_reduce_p(const float* __restrict__ Gp,
                                                   const float* __restrict__ W,
                                                   float* __restrict__ P) {
  const int j = blockIdx.x;     // 0..63
  const int d = threadIdx.x & 63;
  const int q = threadIdx.x >> 6;   // 0..3
  float g = 0.f;
#pragma unroll 8
  for (int i = 0; i < 128; ++i)
    g += Gp[(size_t)(q + 4 * i) * 4096 + j * DIM + d];
  __shared__ float part[4][DIM];
  part[q][d] = g;
  __syncthreads();
  if (q == 0) {
    float row = part[0][d] + part[1][d] + part[2][d] + part[3][d];
    part[0][d] = row;
  }
  __syncthreads();
  if (q == 0) {
    float acc = 0.f;
#pragma unroll
    for (int k = 0; k < DIM; ++k) acc += part[0][k] * W[d * DIM + k];
    P[j * DIM + d] = acc;
  }
}

// ---------- out[n,d] = u[n,d] + (u_n @ P)[d] / (max(s_n,eps)*M) + b[d] ----------
__global__ __launch_bounds__(256) void out_kernel(const float* __restrict__ u,
                                                  const float* __restrict__ P,
                                                  const float* __restrict__ Spart,
                                                  const float* __restrict__ bias,
                                                  float* __restrict__ out) {
  __shared__ float Ps[DIM][DIM];   // 16 KB
  __shared__ float us[4][DIM];
  const int tid = threadIdx.x;
#pragma unroll
  for (int i = 0; i < 16; ++i)
    (&Ps[0][0])[tid + i * 256] = P[tid + i * 256];
  const int base = blockIdx.x * 256;
  us[tid >> 6][tid & 63] = u[base + tid];
  __syncthreads();

  const int nl = tid >> 6;
  const int d = tid & 63;
  const int n = blockIdx.x * 4 + nl;

  float sp = Spart[(size_t)n * 64 + d];
#pragma unroll
  for (int off = 1; off < 64; off <<= 1) sp += __shfl_xor(sp, off, 64);
  const float inv = 1.f / (fmaxf(sp, 1e-12f) * (float)M_ROWS);

  float acc = 0.f;
#pragma unroll
  for (int jj = 0; jj < DIM; ++jj) acc += us[nl][jj] * Ps[jj][d];
  out[base + tid] = us[nl][d] + acc * inv + bias[d];
}

extern "C" void kernel_launch(void* const* d_in, const int* in_sizes, int n_in,
                              void* d_out, int out_size, void* d_ws, size_t ws_size,
                              hipStream_t stream) {
  const float* u  = (const float*)d_in[0];   // [4096,64]
  const float* sf = (const float*)d_in[1];   // [65536,64]
  const float* W  = (const float*)d_in[2];   // [64,64]
  const float* b  = (const float*)d_in[3];   // [64]
  float* out = (float*)d_out;

  char* ws = (char*)d_ws;
  unsigned short* sf16 = (unsigned short*)ws;                // 8,388,608 B
  float* Spart = (float*)(ws + 8388608);                     // 1,048,576 B [4096][64]
  float* Gp    = (float*)(ws + 9437184);                     // 8,388,608 B [512][4096]
  float* P     = (float*)(ws + 17825792);                    //    16,384 B

  cvt_g_kernel<<<dim3(512), 256, 0, stream>>>(sf, sf16, Gp);
  s_kernel<<<dim3(8, 64), 256, 0, stream>>>(u, sf16, Spart);
  gp_reduce_p<<<dim3(64), 256, 0, stream>>>(Gp, W, P);
  out_kernel<<<dim3(N_ROWS * 64 / 256), 256, 0, stream>>>(u, P, Spart, b, out);
}

// Round 5
// 132.468 us; speedup vs baseline: 1.1201x; 1.1201x over previous
//
#include <hip/hip_runtime.h>
#include <hip/hip_bf16.h>

typedef __attribute__((ext_vector_type(8))) short short8v;   // 8 bf16 = 4 VGPRs
typedef __attribute__((ext_vector_type(4))) float f32x4;

#define N_ROWS 4096
#define M_ROWS 65536
#define DIM 64

#define AS1C(p) ((const __attribute__((address_space(1))) void*)(p))
#define AS3(p)  ((__attribute__((address_space(3))) void*)(p))
#define SCHED0() __builtin_amdgcn_sched_barrier(0)

__device__ inline unsigned short f2bf(float f) {
  unsigned u = __float_as_uint(f);
  unsigned r = (u + 0x7FFFu + ((u >> 16) & 1u)) >> 16;   // RNE
  return (unsigned short)r;
}
__device__ inline float bf2f(unsigned short s) {
  return __uint_as_float(((unsigned)s) << 16);
}

// ---------- fused: convert sf f32->bf16 AND partial G = SF^T SF ----------
__global__ __launch_bounds__(256) void cvt_g_kernel(const float* __restrict__ sf,
                                                    unsigned short* __restrict__ sf16,
                                                    float* __restrict__ Gp) {
  __shared__ unsigned short tile[128 * DIM];   // 16 KB
  const int tid = threadIdx.x;
  const size_t base = (size_t)blockIdx.x * 128 * DIM;

#pragma unroll
  for (int j = 0; j < 8; ++j) {
    const int e = tid * 4 + j * 1024;
    float4 v = *reinterpret_cast<const float4*>(sf + base + e);
    ushort4 o;
    o.x = f2bf(v.x); o.y = f2bf(v.y); o.z = f2bf(v.z); o.w = f2bf(v.w);
    *reinterpret_cast<ushort4*>(sf16 + base + e) = o;
    *reinterpret_cast<ushort4*>(&tile[e]) = o;
  }
  __syncthreads();

  const int d1 = (tid & 15) * 4;
  const int d2 = (tid >> 4) * 4;
  float acc[4][4];
#pragma unroll
  for (int i = 0; i < 4; ++i)
#pragma unroll
    for (int j = 0; j < 4; ++j) acc[i][j] = 0.f;

#pragma unroll 8
  for (int m = 0; m < 128; ++m) {
    ushort4 a4 = *reinterpret_cast<const ushort4*>(&tile[m * DIM + d1]);
    ushort4 b4 = *reinterpret_cast<const ushort4*>(&tile[m * DIM + d2]);
    float a[4] = {bf2f(a4.x), bf2f(a4.y), bf2f(a4.z), bf2f(a4.w)};
    float b[4] = {bf2f(b4.x), bf2f(b4.y), bf2f(b4.z), bf2f(b4.w)};
#pragma unroll
    for (int i = 0; i < 4; ++i)
#pragma unroll
      for (int j = 0; j < 4; ++j) acc[i][j] += a[i] * b[j];
  }
#pragma unroll
  for (int i = 0; i < 4; ++i)
#pragma unroll
    for (int j = 0; j < 4; ++j)
      Gp[(size_t)blockIdx.x * 4096 + (d1 + i) * DIM + (d2 + j)] = acc[i][j];
}

// ---------- Spart[n][bm] = sum over m-chunk bm of |u_n . sf_m| ----------
// R3 geometry (grid 16x64, 4 waves x 64 n-rows) + T4 counted-vmcnt pipeline:
// quad-buffered LDS B (4 x 8 KB), stages issued 2 K-steps ahead, raw s_barrier
// with vmcnt(2) (never 0 in steady state). LDS layout [kpart(8)][row(64)][8]
// via per-lane global source address (linear LDS dest, rule #21).
__global__ __launch_bounds__(256, 4) void s_kernel(const float* __restrict__ u,
                                                   const unsigned short* __restrict__ sf16,
                                                   float* __restrict__ Spart) {
  __shared__ unsigned short Bt[4][4096];   // 4 x 8 KB
  const int bn = blockIdx.x;          // 0..15
  const int bm = blockIdx.y;          // 0..63
  const int tid = threadIdx.x;
  const int wid = tid >> 6;
  const int lane = tid & 63;
  const int l15 = lane & 15;
  const int lg  = lane >> 4;          // 0..3
  const int n0 = bn * 256 + wid * 64;
  const int mbase = bm * 1024;

  // A fragments: convert u rows f32->bf16 in-register. A[row=l15][k=kf*32+lg*8+j]
  short8v au[4][2];
#pragma unroll
  for (int st = 0; st < 4; ++st) {
#pragma unroll
    for (int kf = 0; kf < 2; ++kf) {
      const float* ap = u + (size_t)(n0 + st * 16 + l15) * DIM + kf * 32 + lg * 8;
      float4 f0 = *reinterpret_cast<const float4*>(ap);
      float4 f1 = *reinterpret_cast<const float4*>(ap + 4);
      short8v v;
      v[0] = (short)f2bf(f0.x); v[1] = (short)f2bf(f0.y);
      v[2] = (short)f2bf(f0.z); v[3] = (short)f2bf(f0.w);
      v[4] = (short)f2bf(f1.x); v[5] = (short)f2bf(f1.y);
      v[6] = (short)f2bf(f1.z); v[7] = (short)f2bf(f1.w);
      au[st][kf] = v;
    }
  }

  f32x4 sacc[4];
#pragma unroll
  for (int st = 0; st < 4; ++st) sacc[st] = (f32x4){0.f, 0.f, 0.f, 0.f};
  const f32x4 ZERO = (f32x4){0.f, 0.f, 0.f, 0.f};   // persistent C=0 quad

  // Wave w stages kparts {2w, 2w+1}; 2 global_load_lds (16B) per wave per stage.
  //   Bt[buf][kp*512 + lane*8] <- sf16[(mbase + step*64 + lane)*64 + kp*8]
#define STAGE(buf, step)                                                       \
  {                                                                            \
    _Pragma("unroll") for (int j = 0; j < 2; ++j) {                            \
      const int kp = wid * 2 + j;                                              \
      const unsigned short* g =                                                \
          sf16 + (size_t)(mbase + (step) * 64 + lane) * DIM + kp * 8;          \
      __builtin_amdgcn_global_load_lds(AS1C(g),                                \
          AS3(&Bt[0][0] + (size_t)(buf) * 4096 + kp * 512), 16, 0, 0);         \
    }                                                                          \
  }

  STAGE(0, 0);
  STAGE(1, 1);

  const int boff = l15 * 8;   // row-offset within a kpart block

#pragma unroll 1
  for (int s = 0; s < 16; ++s) {
    SCHED0();
    if (s < 15) {
      asm volatile("s_waitcnt vmcnt(2)" ::: "memory");   // own stage-s loads done
    } else {
      asm volatile("s_waitcnt vmcnt(0)" ::: "memory");
    }
    SCHED0();
    __builtin_amdgcn_s_barrier();                        // all waves' stage-s done
    SCHED0();
    if (s < 14) STAGE((s + 2) & 3, s + 2);               // prefetch 2 ahead
    const unsigned short* B = &Bt[0][0] + (size_t)(s & 3) * 4096;
#pragma unroll
    for (int g = 0; g < 4; ++g) {       // 16-row m sub-tiles
      short8v b0 = *reinterpret_cast<const short8v*>(
          &B[(size_t)lg * 512 + g * 128 + boff]);          // kpart = lg
      short8v b1 = *reinterpret_cast<const short8v*>(
          &B[(size_t)(4 + lg) * 512 + g * 128 + boff]);    // kpart = 4+lg
#pragma unroll
      for (int st = 0; st < 4; ++st) {
        f32x4 acc = __builtin_amdgcn_mfma_f32_16x16x32_bf16(au[st][0], b0, ZERO, 0, 0, 0);
        acc = __builtin_amdgcn_mfma_f32_16x16x32_bf16(au[st][1], b1, acc, 0, 0, 0);
        sacc[st][0] += fabsf(acc[0]);
        sacc[st][1] += fabsf(acc[1]);
        sacc[st][2] += fabsf(acc[2]);
        sacc[st][3] += fabsf(acc[3]);
      }
    }
  }
#undef STAGE

  // reduce across the 16 m-columns (lane bits 0..3)
#pragma unroll
  for (int off = 1; off < 16; off <<= 1) {
#pragma unroll
    for (int st = 0; st < 4; ++st) {
#pragma unroll
      for (int r = 0; r < 4; ++r)
        sacc[st][r] += __shfl_xor(sacc[st][r], off, 64);
    }
  }
  if (l15 == 0) {
#pragma unroll
    for (int st = 0; st < 4; ++st)
#pragma unroll
      for (int r = 0; r < 4; ++r)
        Spart[(size_t)(n0 + st * 16 + lg * 4 + r) * 64 + bm] = sacc[st][r];
  }
}

// ---------- reduce Gp (512 partials) -> G row j, then P[j] = G[j] @ W^T ----------
__global__ __launch_bounds__(256) void gp_reduce_p(const float* __restrict__ Gp,
                                                   const float* __restrict__ W,
                                                   float* __restrict__ P) {
  const int j = blockIdx.x;     // 0..63
  const int d = threadIdx.x & 63;
  const int q = threadIdx.x >> 6;   // 0..3
  float g = 0.f;
#pragma unroll 8
  for (int i = 0; i < 128; ++i)
    g += Gp[(size_t)(q + 4 * i) * 4096 + j * DIM + d];
  __shared__ float part[4][DIM];
  part[q][d] = g;
  __syncthreads();
  if (q == 0) {
    float row = part[0][d] + part[1][d] + part[2][d] + part[3][d];
    part[0][d] = row;
  }
  __syncthreads();
  if (q == 0) {
    float acc = 0.f;
#pragma unroll
    for (int k = 0; k < DIM; ++k) acc += part[0][k] * W[d * DIM + k];
    P[j * DIM + d] = acc;
  }
}

// ---------- out[n,d] = u[n,d] + (u_n @ P)[d] / (max(s_n,eps)*M) + b[d] ----------
__global__ __launch_bounds__(256) void out_kernel(const float* __restrict__ u,
                                                  const float* __restrict__ P,
                                                  const float* __restrict__ Spart,
                                                  const float* __restrict__ bias,
                                                  float* __restrict__ out) {
  __shared__ float Ps[DIM][DIM];   // 16 KB
  __shared__ float us[4][DIM];
  const int tid = threadIdx.x;
#pragma unroll
  for (int i = 0; i < 16; ++i)
    (&Ps[0][0])[tid + i * 256] = P[tid + i * 256];
  const int base = blockIdx.x * 256;
  us[tid >> 6][tid & 63] = u[base + tid];
  __syncthreads();

  const int nl = tid >> 6;
  const int d = tid & 63;
  const int n = blockIdx.x * 4 + nl;

  float sp = Spart[(size_t)n * 64 + d];
#pragma unroll
  for (int off = 1; off < 64; off <<= 1) sp += __shfl_xor(sp, off, 64);
  const float inv = 1.f / (fmaxf(sp, 1e-12f) * (float)M_ROWS);

  float acc = 0.f;
#pragma unroll
  for (int jj = 0; jj < DIM; ++jj) acc += us[nl][jj] * Ps[jj][d];
  out[base + tid] = us[nl][d] + acc * inv + bias[d];
}

extern "C" void kernel_launch(void* const* d_in, const int* in_sizes, int n_in,
                              void* d_out, int out_size, void* d_ws, size_t ws_size,
                              hipStream_t stream) {
  const float* u  = (const float*)d_in[0];   // [4096,64]
  const float* sf = (const float*)d_in[1];   // [65536,64]
  const float* W  = (const float*)d_in[2];   // [64,64]
  const float* b  = (const float*)d_in[3];   // [64]
  float* out = (float*)d_out;

  char* ws = (char*)d_ws;
  unsigned short* sf16 = (unsigned short*)ws;                // 8,388,608 B
  float* Spart = (float*)(ws + 8388608);                     // 1,048,576 B [4096][64]
  float* Gp    = (float*)(ws + 9437184);                     // 8,388,608 B [512][4096]
  float* P     = (float*)(ws + 17825792);                    //    16,384 B

  cvt_g_kernel<<<dim3(512), 256, 0, stream>>>(sf, sf16, Gp);
  s_kernel<<<dim3(16, 64), 256, 0, stream>>>(u, sf16, Spart);
  gp_reduce_p<<<dim3(64), 256, 0, stream>>>(Gp, W, P);
  out_kernel<<<dim3(N_ROWS * 64 / 256), 256, 0, stream>>>(u, P, Spart, b, out);
}

// Round 6
// 124.656 us; speedup vs baseline: 1.1903x; 1.0627x over previous
//
#include <hip/hip_runtime.h>
#include <hip/hip_bf16.h>

typedef __attribute__((ext_vector_type(8))) short short8v;   // 8 bf16 = 4 VGPRs
typedef __attribute__((ext_vector_type(4))) float f32x4;

#define N_ROWS 4096
#define M_ROWS 65536
#define DIM 64

#define AS1C(p) ((const __attribute__((address_space(1))) void*)(p))
#define AS3(p)  ((__attribute__((address_space(3))) void*)(p))
#define SCHED0() __builtin_amdgcn_sched_barrier(0)

__device__ inline unsigned short f2bf(float f) {
  unsigned u = __float_as_uint(f);
  unsigned r = (u + 0x7FFFu + ((u >> 16) & 1u)) >> 16;   // RNE
  return (unsigned short)r;
}
__device__ inline float bf2f(unsigned short s) {
  return __uint_as_float(((unsigned)s) << 16);
}

// ---------- fused: convert sf f32->bf16 AND partial G = SF^T SF ----------
__global__ __launch_bounds__(256) void cvt_g_kernel(const float* __restrict__ sf,
                                                    unsigned short* __restrict__ sf16,
                                                    float* __restrict__ Gp) {
  __shared__ unsigned short tile[128 * DIM];   // 16 KB
  const int tid = threadIdx.x;
  const size_t base = (size_t)blockIdx.x * 128 * DIM;

#pragma unroll
  for (int j = 0; j < 8; ++j) {
    const int e = tid * 4 + j * 1024;
    float4 v = *reinterpret_cast<const float4*>(sf + base + e);
    ushort4 o;
    o.x = f2bf(v.x); o.y = f2bf(v.y); o.z = f2bf(v.z); o.w = f2bf(v.w);
    *reinterpret_cast<ushort4*>(sf16 + base + e) = o;
    *reinterpret_cast<ushort4*>(&tile[e]) = o;
  }
  __syncthreads();

  const int d1 = (tid & 15) * 4;
  const int d2 = (tid >> 4) * 4;
  float acc[4][4];
#pragma unroll
  for (int i = 0; i < 4; ++i)
#pragma unroll
    for (int j = 0; j < 4; ++j) acc[i][j] = 0.f;

#pragma unroll 8
  for (int m = 0; m < 128; ++m) {
    ushort4 a4 = *reinterpret_cast<const ushort4*>(&tile[m * DIM + d1]);
    ushort4 b4 = *reinterpret_cast<const ushort4*>(&tile[m * DIM + d2]);
    float a[4] = {bf2f(a4.x), bf2f(a4.y), bf2f(a4.z), bf2f(a4.w)};
    float b[4] = {bf2f(b4.x), bf2f(b4.y), bf2f(b4.z), bf2f(b4.w)};
#pragma unroll
    for (int i = 0; i < 4; ++i)
#pragma unroll
      for (int j = 0; j < 4; ++j) acc[i][j] += a[i] * b[j];
  }
#pragma unroll
  for (int i = 0; i < 4; ++i)
#pragma unroll
    for (int j = 0; j < 4; ++j)
      Gp[(size_t)blockIdx.x * 4096 + (d1 + i) * DIM + (d2 + j)] = acc[i][j];
}

// ---------- Spart[n][bm] = sum over m-chunk bm of |u_n . sf_m| ----------
// Quad-buffered LDS B (4 x 8 KB), counted vmcnt(2), raw s_barrier, K-loop
// fully unrolled x4 so buffer indices / LDS addrs are compile-time. setprio
// around the MFMA cluster. abs-accumulate forced to v_add_f32 |src|.
__global__ __launch_bounds__(256, 4) void s_kernel(const float* __restrict__ u,
                                                   const unsigned short* __restrict__ sf16,
                                                   float* __restrict__ Spart) {
  __shared__ unsigned short Bt[4][4096];   // 4 x 8 KB
  const int bn = blockIdx.x;          // 0..15
  const int bm = blockIdx.y;          // 0..63
  const int tid = threadIdx.x;
  const int wid = tid >> 6;
  const int lane = tid & 63;
  const int l15 = lane & 15;
  const int lg  = lane >> 4;          // 0..3
  const int n0 = bn * 256 + wid * 64;
  const int mbase = bm * 1024;

  // A fragments: convert u rows f32->bf16 in-register. A[row=l15][k=kf*32+lg*8+j]
  short8v au[4][2];
#pragma unroll
  for (int st = 0; st < 4; ++st) {
#pragma unroll
    for (int kf = 0; kf < 2; ++kf) {
      const float* ap = u + (size_t)(n0 + st * 16 + l15) * DIM + kf * 32 + lg * 8;
      float4 f0 = *reinterpret_cast<const float4*>(ap);
      float4 f1 = *reinterpret_cast<const float4*>(ap + 4);
      short8v v;
      v[0] = (short)f2bf(f0.x); v[1] = (short)f2bf(f0.y);
      v[2] = (short)f2bf(f0.z); v[3] = (short)f2bf(f0.w);
      v[4] = (short)f2bf(f1.x); v[5] = (short)f2bf(f1.y);
      v[6] = (short)f2bf(f1.z); v[7] = (short)f2bf(f1.w);
      au[st][kf] = v;
    }
  }

  float sacc[4][4];
#pragma unroll
  for (int st = 0; st < 4; ++st)
#pragma unroll
    for (int r = 0; r < 4; ++r) sacc[st][r] = 0.f;
  const f32x4 ZERO = (f32x4){0.f, 0.f, 0.f, 0.f};

  // Wave w stages kparts {2w, 2w+1}. Running global pointers, +4096 ushorts/step.
  //   Bt[buf][kp*512 + lane*8] <- sf16[(mbase + step*64 + lane)*64 + kp*8]
  const int kp0 = wid * 2, kp1 = wid * 2 + 1;
  const unsigned short* gp0 = sf16 + (size_t)(mbase + lane) * DIM + kp0 * 8;
  const unsigned short* gp1 = sf16 + (size_t)(mbase + lane) * DIM + kp1 * 8;

#define STAGE2(BUF)                                                            \
  {                                                                            \
    __builtin_amdgcn_global_load_lds(AS1C(gp0), AS3(&Bt[BUF][kp0 * 512]), 16, 0, 0); \
    __builtin_amdgcn_global_load_lds(AS1C(gp1), AS3(&Bt[BUF][kp1 * 512]), 16, 0, 0); \
    gp0 += 4096; gp1 += 4096;                                                  \
  }

#define ABSADD(S, A)                                                           \
  { float _a = (A); asm("v_add_f32_e64 %0, %0, |%1|" : "+v"(S) : "v"(_a)); }

  const int bofs = lg * 512 + l15 * 8;   // ushort offset of this lane's row slot

#define STEP(BUF, LAST, STAGECODE)                                             \
  {                                                                            \
    if (LAST) { asm volatile("s_waitcnt vmcnt(0)" ::: "memory"); }             \
    else      { asm volatile("s_waitcnt vmcnt(2)" ::: "memory"); }             \
    __builtin_amdgcn_s_barrier();                                              \
    SCHED0();                                                                  \
    STAGECODE;                                                                 \
    {                                                                          \
      const unsigned short* B = &Bt[BUF][0];                                   \
      __builtin_amdgcn_s_setprio(1);                                           \
      _Pragma("unroll") for (int g = 0; g < 4; ++g) {                          \
        short8v b0 = *reinterpret_cast<const short8v*>(&B[bofs + g * 128]);    \
        short8v b1 = *reinterpret_cast<const short8v*>(&B[bofs + 2048 + g * 128]); \
        _Pragma("unroll") for (int st = 0; st < 4; ++st) {                     \
          f32x4 acc = __builtin_amdgcn_mfma_f32_16x16x32_bf16(au[st][0], b0, ZERO, 0, 0, 0); \
          acc = __builtin_amdgcn_mfma_f32_16x16x32_bf16(au[st][1], b1, acc, 0, 0, 0); \
          ABSADD(sacc[st][0], acc[0]);                                         \
          ABSADD(sacc[st][1], acc[1]);                                         \
          ABSADD(sacc[st][2], acc[2]);                                         \
          ABSADD(sacc[st][3], acc[3]);                                         \
        }                                                                      \
      }                                                                        \
      __builtin_amdgcn_s_setprio(0);                                           \
    }                                                                          \
  }

  STAGE2(0);
  STAGE2(1);

#pragma unroll 1
  for (int s4 = 0; s4 < 3; ++s4) {       // steps 0..11
    STEP(0, false, STAGE2(2));
    STEP(1, false, STAGE2(3));
    STEP(2, false, STAGE2(0));
    STEP(3, false, STAGE2(1));
  }
  STEP(0, false, STAGE2(2));             // step 12 (stages 14)
  STEP(1, false, STAGE2(3));             // step 13 (stages 15)
  STEP(2, false, (void)0);               // step 14
  STEP(3, true,  (void)0);               // step 15

#undef STEP
#undef STAGE2

  // reduce across the 16 m-columns (lane bits 0..3)
#pragma unroll
  for (int off = 1; off < 16; off <<= 1) {
#pragma unroll
    for (int st = 0; st < 4; ++st) {
#pragma unroll
      for (int r = 0; r < 4; ++r)
        sacc[st][r] += __shfl_xor(sacc[st][r], off, 64);
    }
  }
  if (l15 == 0) {
#pragma unroll
    for (int st = 0; st < 4; ++st)
#pragma unroll
      for (int r = 0; r < 4; ++r)
        Spart[(size_t)(n0 + st * 16 + lg * 4 + r) * 64 + bm] = sacc[st][r];
  }
}

// ---------- reduce Gp (512 partials) -> G row j, then P[j] = G[j] @ W^T ----------
__global__ __launch_bounds__(256) void gp_reduce_p(const float* __restrict__ Gp,
                                                   const float* __restrict__ W,
                                                   float* __restrict__ P) {
  const int j = blockIdx.x;     // 0..63
  const int d = threadIdx.x & 63;
  const int q = threadIdx.x >> 6;   // 0..3
  float g = 0.f;
#pragma unroll 8
  for (int i = 0; i < 128; ++i)
    g += Gp[(size_t)(q + 4 * i) * 4096 + j * DIM + d];
  __shared__ float part[4][DIM];
  part[q][d] = g;
  __syncthreads();
  if (q == 0) {
    float row = part[0][d] + part[1][d] + part[2][d] + part[3][d];
    part[0][d] = row;
  }
  __syncthreads();
  if (q == 0) {
    float acc = 0.f;
#pragma unroll
    for (int k = 0; k < DIM; ++k) acc += part[0][k] * W[d * DIM + k];
    P[j * DIM + d] = acc;
  }
}

// ---------- out[n,d] = u[n,d] + (u_n @ P)[d] / (max(s_n,eps)*M) + b[d] ----------
__global__ __launch_bounds__(256) void out_kernel(const float* __restrict__ u,
                                                  const float* __restrict__ P,
                                                  const float* __restrict__ Spart,
                                                  const float* __restrict__ bias,
                                                  float* __restrict__ out) {
  __shared__ float Ps[DIM][DIM];   // 16 KB
  __shared__ float us[4][DIM];
  const int tid = threadIdx.x;
#pragma unroll
  for (int i = 0; i < 16; ++i)
    (&Ps[0][0])[tid + i * 256] = P[tid + i * 256];
  const int base = blockIdx.x * 256;
  us[tid >> 6][tid & 63] = u[base + tid];
  __syncthreads();

  const int nl = tid >> 6;
  const int d = tid & 63;
  const int n = blockIdx.x * 4 + nl;

  float sp = Spart[(size_t)n * 64 + d];
#pragma unroll
  for (int off = 1; off < 64; off <<= 1) sp += __shfl_xor(sp, off, 64);
  const float inv = 1.f / (fmaxf(sp, 1e-12f) * (float)M_ROWS);

  float acc = 0.f;
#pragma unroll
  for (int jj = 0; jj < DIM; ++jj) acc += us[nl][jj] * Ps[jj][d];
  out[base + tid] = us[nl][d] + acc * inv + bias[d];
}

extern "C" void kernel_launch(void* const* d_in, const int* in_sizes, int n_in,
                              void* d_out, int out_size, void* d_ws, size_t ws_size,
                              hipStream_t stream) {
  const float* u  = (const float*)d_in[0];   // [4096,64]
  const float* sf = (const float*)d_in[1];   // [65536,64]
  const float* W  = (const float*)d_in[2];   // [64,64]
  const float* b  = (const float*)d_in[3];   // [64]
  float* out = (float*)d_out;

  char* ws = (char*)d_ws;
  unsigned short* sf16 = (unsigned short*)ws;                // 8,388,608 B
  float* Spart = (float*)(ws + 8388608);                     // 1,048,576 B [4096][64]
  float* Gp    = (float*)(ws + 9437184);                     // 8,388,608 B [512][4096]
  float* P     = (float*)(ws + 17825792);                    //    16,384 B

  cvt_g_kernel<<<dim3(512), 256, 0, stream>>>(sf, sf16, Gp);
  s_kernel<<<dim3(16, 64), 256, 0, stream>>>(u, sf16, Spart);
  gp_reduce_p<<<dim3(64), 256, 0, stream>>>(Gp, W, P);
  out_kernel<<<dim3(N_ROWS * 64 / 256), 256, 0, stream>>>(u, P, Spart, b, out);
}